// Round 15
// baseline (699.545 us; speedup 1.0000x reference)
//
#include <hip/hip_runtime.h>
#include <hip/hip_fp8.h>

typedef __attribute__((ext_vector_type(8))) short short8;
typedef __attribute__((ext_vector_type(4))) float f32x4;
typedef __attribute__((ext_vector_type(2))) long longx2;   // 16B: two fp8 A-frags (ks, ks+1)

#define NB 16384
#define DDIM 1024
#define AD 512
#define CTR_OFF 3407872   // barrier counters just past the packed weights

static __device__ __forceinline__ unsigned short f2bf(float f){
  unsigned int u = __float_as_uint(f);
  u += 0x7FFFu + ((u >> 16) & 1u);
  return (unsigned short)(u >> 16);
}
static __device__ __forceinline__ float bf2f(short s){
  return __uint_as_float(((unsigned int)(unsigned short)s) << 16);
}
// SOFTWARE conversions (r12/r13 lesson): schedulable op count beats raw op
// count in latency-critical epilogues; HW cvt_pk asm forms regressed.
static __device__ __forceinline__ unsigned long long pack4(float a, float b, float c, float d){
  return (unsigned long long)f2bf(a) | ((unsigned long long)f2bf(b) << 16)
       | ((unsigned long long)f2bf(c) << 32) | ((unsigned long long)f2bf(d) << 48);
}
static __device__ __forceinline__ unsigned char f2e4(float f){
  return __hip_fp8_e4m3(f).__x;
}
static __device__ __forceinline__ unsigned int pack4f8(float a, float b, float c, float d){
  return (unsigned)f2e4(a) | ((unsigned)f2e4(b) << 8) | ((unsigned)f2e4(c) << 16) | ((unsigned)f2e4(d) << 24);
}
static __device__ __forceinline__ float softplusf(float z){
  return fmaxf(z, 0.f) + log1pf(expf(-fabsf(z)));
}
static __device__ __forceinline__ float softf(float z, float th){
  return copysignf(fmaxf(fabsf(z) - th, 0.f), z);
}

// LDS-only barrier: waits local ops, does NOT drain vmcnt.
static __device__ __forceinline__ void bar_lds(){
  __builtin_amdgcn_sched_barrier(0);
  asm volatile("s_waitcnt lgkmcnt(0)" ::: "memory");
  __builtin_amdgcn_s_barrier();
  __builtin_amdgcn_sched_barrier(0);
}

// Best-effort PER-XCD alignment barrier (PERFORMANCE ONLY). One L2 fill
// serves all 32 blocks of an XCD when their weight walks coincide
// (r8: FETCH 1.03GB->495MB; r11: per-XCD form beats grid form by 22us).
// Bounded spin; counters reset by pack_all each launch (graph-safe).
static __device__ __forceinline__ void xcd_align(unsigned* ctrs, int site,
                                                 int tid, unsigned bid,
                                                 unsigned target){
  unsigned* ctr = ctrs + site * 8 + (bid & 7);
  if (tid == 0){
    __hip_atomic_fetch_add(ctr, 1u, __ATOMIC_RELAXED, __HIP_MEMORY_SCOPE_AGENT);
    for (int i = 0; i < 8000; ++i){
      if (__hip_atomic_load(ctr, __ATOMIC_RELAXED, __HIP_MEMORY_SCOPE_AGENT) >= target)
        break;
      __builtin_amdgcn_s_sleep(2);
    }
  }
  bar_lds();
}

// Pack W[K][N] (f32 row-major, stride ldn) into per-lane MFMA A-fragments.
// bf16 frag: 16B/lane at (frag*64+lane)*16, frag = nt*KS+ks.
// fp8 frag: 8B/lane, PAIR-INTERLEAVED for 16B loads: byte addr =
//   (pair*64+lane)*16 + (ks&1)*8, pair = nt*(KS/2)+ks/2.
__global__ void pack_all(const float* __restrict__ W_proj, const float* __restrict__ W_rec,
                         const float* __restrict__ W_pres, const float* __restrict__ W_sign,
                         const float* __restrict__ W_g1,   const float* __restrict__ W_g2,
                         const float* __restrict__ W_k,    const float* __restrict__ W_t,
                         unsigned char* __restrict__ ws){
  if (blockIdx.x == 0 && threadIdx.x < 64)
    __hip_atomic_store((unsigned*)(ws + CTR_OFF) + threadIdx.x, 0u,
                       __ATOMIC_RELAXED, __HIP_MEMORY_SCOPE_AGENT);
  int t = blockIdx.x * 256 + threadIdx.x;
  const float* W; size_t off; int KS, NT, ldn, isbf; float scl = 16.f;
  if      (t < 32768) {              W = W_rec;                   off = 0;       KS = 16; NT = 32; ldn = 512;  isbf = 1; }
  else if (t < 98304) { t -= 32768;  W = W_proj;                  off = 524288;  KS = 32; NT = 32; ldn = 512;  isbf = 0; }
  else if (t < 163840){ t -= 98304;  W = W_pres;                  off = 1048576; KS = 16; NT = 64; ldn = 1024; isbf = 0; }
  else if (t < 196608){ t -= 163840; W = W_sign;                  off = 1572864; KS = 16; NT = 32; ldn = 512;  isbf = 0; }
  else if (t < 262144){ t -= 196608; W = W_g1;                    off = 1835008; KS = 32; NT = 32; ldn = 512;  isbf = 0; scl = 4.f; }
  else if (t < 294912){ t -= 262144; W = W_g1 + (size_t)1025*512; off = 2359296; KS = 16; NT = 32; ldn = 512;  isbf = 0; }
  else if (t < 327680){ t -= 294912; W = W_g2;                    off = 2621440; KS = 16; NT = 32; ldn = 512;  isbf = 0; }
  else if (t < 360448){ t -= 327680; W = W_k;                     off = 2883584; KS = 16; NT = 32; ldn = 512;  isbf = 0; }
  else if (t < 393216){ t -= 360448; W = W_t;                     off = 3145728; KS = 16; NT = 32; ldn = 512;  isbf = 0; }
  else return;
  int lane = t & 63;
  int frag = t >> 6;
  int ks = frag % KS;
  int nt = frag / KS;
  int col = nt * 16 + (lane & 15);
  int k0 = ks * 32 + ((lane >> 4) << 3);
  const float* src = W + (size_t)k0 * ldn + col;
  if (isbf){
    short8 v;
#pragma unroll
    for (int j = 0; j < 8; ++j) v[j] = (short)f2bf(src[(size_t)j * ldn]);
    *(short8*)(ws + off + ((size_t)frag * 64 + lane) * 16) = v;
  } else {
    unsigned long long v = 0;
#pragma unroll
    for (int j = 0; j < 8; ++j)
      v |= (unsigned long long)f2e4(src[(size_t)j * ldn] * scl) << (8 * j);
    int pair = nt * (KS >> 1) + (ks >> 1);
    *(unsigned long long*)(ws + off + ((size_t)pair * 64 + lane) * 16 + ((size_t)(ks & 1) << 3)) = v;
  }
}

// ---- r15 split-row geometry: wave owns 4 col-frags x 2 row-frags ----
// (waves 0-7: rows 0-31; waves 8-15: rows 32-63; cols (wid&7)*64..+63).
// Per-wave LDS B-reads HALVE (2 rf not 4) in every GEMM; A-frags are read
// by 2 waves each (L2-served, bandwidth ample, HBM fill unchanged).

// bf16 GEMM: B = h in LDS [64 rows][1024B] XOR<<4 swizzle; 4 A-streams.
__device__ __forceinline__ void gemm_bf16(const unsigned char* __restrict__ hb,
    const unsigned char* __restrict__ A, int lane, int rbase, f32x4 acc[4][2]){
  const int c16 = lane & 15;
  const int g16 = (lane >> 4) << 4;
  const int swz = ((c16 & 7) << 4) ^ g16;   // row&7 == c16&7 for both rf
  const unsigned char* bp0 = hb + (size_t)(rbase + c16) * 1024;
  const unsigned char* bp1 = hb + (size_t)(rbase + 16 + c16) * 1024;
  const unsigned char* ap = A + lane * 16;
  short8 af0 = *(const short8*)(ap);
  short8 af1 = *(const short8*)(ap + 16384);
  short8 af2 = *(const short8*)(ap + 32768);
  short8 af3 = *(const short8*)(ap + 49152);
#pragma unroll
  for (int ks = 0; ks < 16; ++ks){
    short8 u0 = af0, u1 = af1, u2 = af2, u3 = af3;
    if (ks < 15){
      ap += 1024;
      af0 = *(const short8*)(ap);
      af1 = *(const short8*)(ap + 16384);
      af2 = *(const short8*)(ap + 32768);
      af3 = *(const short8*)(ap + 49152);
    }
    int kb = ks * 64;
    short8 b0 = *(const short8*)(bp0 + (kb ^ swz));
    short8 b1 = *(const short8*)(bp1 + (kb ^ swz));
    __builtin_amdgcn_s_setprio(1);
    acc[0][0] = __builtin_amdgcn_mfma_f32_16x16x32_bf16(u0, b0, acc[0][0], 0, 0, 0);
    acc[0][1] = __builtin_amdgcn_mfma_f32_16x16x32_bf16(u0, b1, acc[0][1], 0, 0, 0);
    acc[1][0] = __builtin_amdgcn_mfma_f32_16x16x32_bf16(u1, b0, acc[1][0], 0, 0, 0);
    acc[1][1] = __builtin_amdgcn_mfma_f32_16x16x32_bf16(u1, b1, acc[1][1], 0, 0, 0);
    acc[2][0] = __builtin_amdgcn_mfma_f32_16x16x32_bf16(u2, b0, acc[2][0], 0, 0, 0);
    acc[2][1] = __builtin_amdgcn_mfma_f32_16x16x32_bf16(u2, b1, acc[2][1], 0, 0, 0);
    acc[3][0] = __builtin_amdgcn_mfma_f32_16x16x32_bf16(u3, b0, acc[3][0], 0, 0, 0);
    acc[3][1] = __builtin_amdgcn_mfma_f32_16x16x32_bf16(u3, b1, acc[3][1], 0, 0, 0);
    __builtin_amdgcn_s_setprio(0);
  }
}

// fp8 GEMM: A pair-packed (16B/lane = 2 ks), 4 col-frag streams; B fp8 LDS
// tile row-stride RS, XOR<<3 swizzle (row&15 == c16 for both rf).
template<int KSRUN, int RS>
__device__ __forceinline__ void gemm_fp8(const unsigned char* __restrict__ bb,
    const unsigned char* __restrict__ A, int lane, int rbase, f32x4 acc[4][2]){
  const int c16 = lane & 15;
  const int g8 = (lane >> 4) << 3;
  const int swz = (c16 << 3) ^ g8;
  const unsigned char* bp0 = bb + (size_t)(rbase + c16) * RS;
  const unsigned char* bp1 = bb + (size_t)(rbase + 16 + c16) * RS;
  const size_t cfs = (size_t)KSRUN * 512;   // column-frag stride
  const unsigned char* ap = A + lane * 16;
  longx2 f0 = *(const longx2*)(ap);
  longx2 f1 = *(const longx2*)(ap + cfs);
  longx2 f2 = *(const longx2*)(ap + 2 * cfs);
  longx2 f3 = *(const longx2*)(ap + 3 * cfs);
#pragma unroll
  for (int p = 0; p < KSRUN / 2; ++p){
    longx2 u0 = f0, u1 = f1, u2 = f2, u3 = f3;
    if (p < KSRUN / 2 - 1){
      ap += 1024;
      f0 = *(const longx2*)(ap);
      f1 = *(const longx2*)(ap + cfs);
      f2 = *(const longx2*)(ap + 2 * cfs);
      f3 = *(const longx2*)(ap + 3 * cfs);
    }
#pragma unroll
    for (int h = 0; h < 2; ++h){
      int kb = (p * 2 + h) * 32;
      long b0 = *(const long*)(bp0 + (kb ^ swz));
      long b1 = *(const long*)(bp1 + (kb ^ swz));
      __builtin_amdgcn_s_setprio(1);
      acc[0][0] = __builtin_amdgcn_mfma_f32_16x16x32_fp8_fp8(u0[h], b0, acc[0][0], 0, 0, 0);
      acc[0][1] = __builtin_amdgcn_mfma_f32_16x16x32_fp8_fp8(u0[h], b1, acc[0][1], 0, 0, 0);
      acc[1][0] = __builtin_amdgcn_mfma_f32_16x16x32_fp8_fp8(u1[h], b0, acc[1][0], 0, 0, 0);
      acc[1][1] = __builtin_amdgcn_mfma_f32_16x16x32_fp8_fp8(u1[h], b1, acc[1][1], 0, 0, 0);
      acc[2][0] = __builtin_amdgcn_mfma_f32_16x16x32_fp8_fp8(u2[h], b0, acc[2][0], 0, 0, 0);
      acc[2][1] = __builtin_amdgcn_mfma_f32_16x16x32_fp8_fp8(u2[h], b1, acc[2][1], 0, 0, 0);
      acc[3][0] = __builtin_amdgcn_mfma_f32_16x16x32_fp8_fp8(u3[h], b0, acc[3][0], 0, 0, 0);
      acc[3][1] = __builtin_amdgcn_mfma_f32_16x16x32_fp8_fp8(u3[h], b1, acc[3][1], 0, 0, 0);
      __builtin_amdgcn_s_setprio(0);
    }
  }
}

#define ZERO_ACC(A) { _Pragma("unroll") for (int c_=0;c_<4;++c_) _Pragma("unroll") for(int r_=0;r_<2;++r_){ f32x4 z_ = {0.f,0.f,0.f,0.f}; A[c_][r_]=z_; } }

// write one f32x4 (4 consecutive out-cols) as bf16x4 into the 64x512 bf16 bounce tile
static __device__ __forceinline__ void tile_write(unsigned char* tile, int row, int colb, f32x4 v){
  *(unsigned long long*)(tile + (size_t)row * 1024 + (colb ^ ((row & 7) << 4))) = pack4(v[0], v[1], v[2], v[3]);
}

// stream the 64x512 bf16 bounce tile to global f32, non-temporal, full-sector
// (r10: contiguous 256B per 16-lane group -> no partial 64B sectors).
static __device__ __forceinline__ void tile_store(const unsigned char* __restrict__ tile,
    float* __restrict__ dst, int ldo, int wid, int lane){
  int row = wid * 4 + (lane >> 4);
  const unsigned char* rp = tile + (size_t)row * 1024;
  float* orow = dst + (size_t)row * ldo;
  int sw = (row & 7) << 4;
  int l4 = lane & 15;
#pragma unroll
  for (int j = 0; j < 8; ++j){
    int cbyte = j * 128 + l4 * 8;             // bf16 cols j*64 + l4*4 .. +3
    unsigned long long v = *(const unsigned long long*)(rp + (cbyte ^ sw));
    f32x4 o;
    o[0] = bf2f((short)v);         o[1] = bf2f((short)(v >> 16));
    o[2] = bf2f((short)(v >> 32)); o[3] = bf2f((short)(v >> 48));
    __builtin_nontemporal_store(o, (f32x4*)(orow + j * 64 + l4 * 4));
  }
}

__global__ __launch_bounds__(1024, 4) void polar_main(
    const float* __restrict__ x,
    const float* __restrict__ b_proj,
    const float* __restrict__ log_th,
    const float* __restrict__ b_pres,
    const float* __restrict__ b_sign,
    const float* __restrict__ W_g1,
    const float* __restrict__ b_g1,
    const float* __restrict__ b_g2,
    const float* __restrict__ b_k,
    const float* __restrict__ b_t,
    const unsigned char* __restrict__ ws,
    float* __restrict__ out)
{
  // LDS: hbuf 64x512 bf16 (64K) | xbuf 64x1024 fp8 (64K, x*4) | aux 64x512 fp8 (32K)
  __shared__ __align__(128) unsigned char smem[163840];
  unsigned char* hbuf = smem;
  unsigned char* xbuf = smem + 65536;
  unsigned char* aux  = smem + 131072;
  float* recip_s = (float*)aux;
  float* gain_s  = (float*)(aux + 256);

  const unsigned char* Prec  = ws;
  const unsigned char* Pproj = ws + 524288;
  const unsigned char* Ppres = ws + 1048576;
  const unsigned char* Psign = ws + 1572864;
  const unsigned char* Pg1x  = ws + 1835008;
  const unsigned char* Pg1h  = ws + 2359296;
  const unsigned char* Pg2   = ws + 2621440;
  const unsigned char* Pk    = ws + 2883584;
  const unsigned char* Pt    = ws + 3145728;
  unsigned* gctr = (unsigned*)(size_t)(ws + CTR_OFF);

  const int tid = threadIdx.x;
  const int lane = tid & 63;
  const int wid = tid >> 6;        // 0..15
  const unsigned bid = blockIdx.x;
  const int row0 = bid * 64;
  const int c16 = lane & 15;
  const int g2r = (lane >> 4) << 2;
  const unsigned XTGT = gridDim.x >> 3;   // blocks per XCD group (=32)
  const int wc = wid & 7;          // col group: cols wc*64 .. +63
  const int RB = (wid >> 3) * 32;  // row base: 0 or 32

  float* out_k     = out;
  float* out_th    = out + (size_t)NB * AD;
  float* out_pres  = out + (size_t)2 * NB * AD;
  float* out_sign  = out + (size_t)4 * NB * AD;
  float* out_scale = out + (size_t)5 * NB * AD;
  float* out_hd    = out_scale + NB;
  float* out_hg    = out_hd + (size_t)NB * AD;

  // ---------------- Phase 1a: NT-load x, stage fp8(4x) into xbuf, row norms ----------------
  {
    int r = tid >> 4, sub = tid & 15;
    const float* xr = x + (size_t)(row0 + r) * DDIM + sub * 64;
    float ss = 0.f;
#pragma unroll
    for (int i = 0; i < 8; ++i){
      f32x4 v0 = __builtin_nontemporal_load((const f32x4*)(xr + i * 8));
      f32x4 v1 = __builtin_nontemporal_load((const f32x4*)(xr + i * 8 + 4));
      ss += v0[0]*v0[0] + v0[1]*v0[1] + v0[2]*v0[2] + v0[3]*v0[3]
          + v1[0]*v1[0] + v1[1]*v1[1] + v1[2]*v1[2] + v1[3]*v1[3];
      unsigned long long w = (unsigned long long)pack4f8(v0[0]*4.f, v0[1]*4.f, v0[2]*4.f, v0[3]*4.f)
                           | ((unsigned long long)pack4f8(v1[0]*4.f, v1[1]*4.f, v1[2]*4.f, v1[3]*4.f) << 32);
      int cbyte = sub * 64 + i * 8;
      *(unsigned long long*)(xbuf + (size_t)r * 1024 + (cbyte ^ ((r & 15) << 3))) = w;
    }
    ss += __shfl_xor(ss, 1);
    ss += __shfl_xor(ss, 2);
    ss += __shfl_xor(ss, 4);
    ss += __shfl_xor(ss, 8);
    if (sub == 0){
      float norm = sqrtf(ss);
      recip_s[r] = 1.f / (norm + 1e-6f);
      gain_s[r]  = logf(norm + 1e-6f);
      __builtin_nontemporal_store(norm, out_scale + row0 + r);
    }
  }
  bar_lds();

  float rn[2], gn[2];
#pragma unroll
  for (int rf = 0; rf < 2; ++rf){
    rn[rf] = recip_s[RB + rf * 16 + c16];
    gn[rf] = gain_s[RB + rf * 16 + c16];
  }

  // align XCD group before the Pproj walk (site 0)
  xcd_align(gctr, 0, tid, bid, XTGT);

  f32x4 acc[4][2];

  // ---------------- Phase 1b: drive = (x @ W_proj) * rn/64 + b ----------------
  ZERO_ACC(acc);
  gemm_fp8<32, 1024>(xbuf, Pproj + (size_t)(wc * 4) * 32 * 512, lane, RB, acc);

  f32x4 dr[4][2];
  f32x4 th4[4];
#pragma unroll
  for (int cf = 0; cf < 4; ++cf){
    int col0 = wc * 64 + cf * 16 + g2r;
    f32x4 lt = *(const f32x4*)(log_th + col0);
    f32x4 bp = *(const f32x4*)(b_proj + col0);
#pragma unroll
    for (int r = 0; r < 4; ++r) th4[cf][r] = expf(lt[r]);
#pragma unroll
    for (int rf = 0; rf < 2; ++rf)
#pragma unroll
      for (int r = 0; r < 4; ++r)
        dr[cf][rf][r] = acc[cf][rf][r] * (rn[rf] * (1.f / 64.f)) + bp[r];
  }
  // h0 -> hbuf
#pragma unroll
  for (int cf = 0; cf < 4; ++cf){
    int colb = (wc * 64 + cf * 16 + g2r) * 2;
#pragma unroll
    for (int rf = 0; rf < 2; ++rf){
      f32x4 hv;
#pragma unroll
      for (int r = 0; r < 4; ++r) hv[r] = softf(dr[cf][rf][r], th4[cf][r]);
      tile_write(hbuf, RB + rf * 16 + c16, colb, hv);
    }
  }
  bar_lds();

  // ---------------- Phase 2: 15 LISTA iterations (bf16, h in hbuf) ----------------
  const unsigned char* Arec = Prec + (size_t)(wc * 4) * 16 * 1024;
#pragma unroll 1
  for (int it = 0; it < 15; ++it){
    if (it == 8) xcd_align(gctr, 1, tid, bid, XTGT);   // re-align mid-LISTA (site 1)
    ZERO_ACC(acc);
    gemm_bf16(hbuf, Arec, lane, RB, acc);
    bar_lds();               // all h reads done before overwrite
#pragma unroll
    for (int cf = 0; cf < 4; ++cf){
      int col0 = wc * 64 + cf * 16 + g2r;
#pragma unroll
      for (int rf = 0; rf < 2; ++rf){
        int row = RB + rf * 16 + c16;
        f32x4 hv;
#pragma unroll
        for (int r = 0; r < 4; ++r)
          hv[r] = softf(dr[cf][rf][r] + acc[cf][rf][r], th4[cf][r]);
        tile_write(hbuf, row, col0 * 2, hv);
        if (it == 14)          // also stage h as fp8 for phase 3
          *(unsigned int*)(aux + (size_t)row * 512 + (col0 ^ (c16 << 3))) =
              pack4f8(hv[0], hv[1], hv[2], hv[3]);
      }
    }
    bar_lds();
  }

  // ---------------- Phase 3: heads ----------------
  f32x4 acc2[4][2];

  // align XCD group before the Ppres walk (site 2)
  xcd_align(gctr, 2, tid, bid, XTGT);

  // h_delta out (bounce = hbuf itself, already bf16); NT stores drain under
  // the pres GEMM that follows (no vmcnt drain at barriers).
  tile_store(hbuf, out_hd + (size_t)row0 * AD, AD, wid, lane);

  // 3a: presence half 0
  ZERO_ACC(acc);
  gemm_fp8<16, 512>(aux, Ppres + (size_t)(wc * 4) * 16 * 512, lane, RB, acc);
  bar_lds();                   // h_delta reads of hbuf complete

#pragma unroll
  for (int cf = 0; cf < 4; ++cf){
    int col0 = wc * 64 + cf * 16 + g2r;
    f32x4 bv = *(const f32x4*)(b_pres + col0);
#pragma unroll
    for (int rf = 0; rf < 2; ++rf){
      f32x4 o;
#pragma unroll
      for (int r = 0; r < 4; ++r) o[r] = acc[cf][rf][r] * (1.f / 16.f) + bv[r];
      tile_write(hbuf, RB + rf * 16 + c16, col0 * 2, o);
    }
  }
  bar_lds();
  tile_store(hbuf, out_pres + (size_t)row0 * 1024, 1024, wid, lane);

  // align XCD group before the pres-half1 walk (site 4)
  xcd_align(gctr, 4, tid, bid, XTGT);

  // presence half 1 GEMM (aux still holds h-fp8; A-stream overlaps half0 store drain)
  ZERO_ACC(acc2);
  gemm_fp8<16, 512>(aux, Ppres + (size_t)(32 + wc * 4) * 16 * 512, lane, RB, acc2);
  bar_lds();                   // half0 bounce reads complete

#pragma unroll
  for (int cf = 0; cf < 4; ++cf){
    int col0 = wc * 64 + cf * 16 + g2r;
    f32x4 bv = *(const f32x4*)(b_pres + 512 + col0);
#pragma unroll
    for (int rf = 0; rf < 2; ++rf){
      f32x4 o;
#pragma unroll
      for (int r = 0; r < 4; ++r) o[r] = acc2[cf][rf][r] * (1.f / 16.f) + bv[r];
      tile_write(hbuf, RB + rf * 16 + c16, col0 * 2, o);
    }
  }
  bar_lds();
  tile_store(hbuf, out_pres + (size_t)row0 * 1024 + 512, 1024, wid, lane);

  // 3b: sign GEMM (A-stream overlaps half1 store drain)
  ZERO_ACC(acc);
  gemm_fp8<16, 512>(aux, Psign + (size_t)(wc * 4) * 16 * 512, lane, RB, acc);
  bar_lds();                   // half1 bounce reads complete

#pragma unroll
  for (int cf = 0; cf < 4; ++cf){
    int col0 = wc * 64 + cf * 16 + g2r;
    f32x4 bv = *(const f32x4*)(b_sign + col0);
#pragma unroll
    for (int rf = 0; rf < 2; ++rf){
      f32x4 o;
#pragma unroll
      for (int r = 0; r < 4; ++r) o[r] = acc[cf][rf][r] * (1.f / 16.f) + bv[r];
      tile_write(hbuf, RB + rf * 16 + c16, col0 * 2, o);
    }
  }
  bar_lds();
  tile_store(hbuf, out_sign + (size_t)row0 * AD, AD, wid, lane);

  // align XCD group before the gamma-chain weight walk (site 3)
  xcd_align(gctr, 3, tid, bid, XTGT);

  // ---------------- Phase 3c: hg1 = relu(x@Wg1x + h@Wg1h/16 + gain*wg + b) ----------------
  // Pg1x packed at x4 -> x(4)*w(4)=16, matches h(1)*w(16)=16: single /16 epilogue.
  {
    ZERO_ACC(acc);
    gemm_fp8<32, 1024>(xbuf, Pg1x + (size_t)(wc * 4) * 32 * 512, lane, RB, acc);
    gemm_fp8<16, 512>(aux, Pg1h + (size_t)(wc * 4) * 16 * 512, lane, RB, acc);

    f32x4 bv[4], wg[4];
#pragma unroll
    for (int cf = 0; cf < 4; ++cf){
      int col0 = wc * 64 + cf * 16 + g2r;
      bv[cf] = *(const f32x4*)(b_g1 + col0);
      wg[cf] = *(const f32x4*)(W_g1 + (size_t)1024 * AD + col0);
    }
    bar_lds();   // all aux (h-fp8) reads + sign bounce reads done
#pragma unroll
    for (int cf = 0; cf < 4; ++cf){
      int col0 = wc * 64 + cf * 16 + g2r;
#pragma unroll
      for (int rf = 0; rf < 2; ++rf){
        int row = RB + rf * 16 + c16;
        float z0 = fmaxf(acc[cf][rf][0] * (1.f/16.f) + gn[rf] * wg[cf][0] + bv[cf][0], 0.f);
        float z1 = fmaxf(acc[cf][rf][1] * (1.f/16.f) + gn[rf] * wg[cf][1] + bv[cf][1], 0.f);
        float z2 = fmaxf(acc[cf][rf][2] * (1.f/16.f) + gn[rf] * wg[cf][2] + bv[cf][2], 0.f);
        float z3 = fmaxf(acc[cf][rf][3] * (1.f/16.f) + gn[rf] * wg[cf][3] + bv[cf][3], 0.f);
        *(unsigned int*)(aux + (size_t)row * 512 + (col0 ^ (c16 << 3))) =
            pack4f8(z0, z1, z2, z3);
      }
    }
    bar_lds();
  }

  // ---------------- Phase 3d: hg = relu(hg1 @ W_g2 /16 + b_g2) ----------------
  {
    // align XCD group before the Pg2 walk (site 5)
    xcd_align(gctr, 5, tid, bid, XTGT);
    ZERO_ACC(acc);
    gemm_fp8<16, 512>(aux, Pg2 + (size_t)(wc * 4) * 16 * 512, lane, RB, acc);
    f32x4 bv[4];
#pragma unroll
    for (int cf = 0; cf < 4; ++cf)
      bv[cf] = *(const f32x4*)(b_g2 + wc * 64 + cf * 16 + g2r);
    bar_lds();   // all hg1 reads done before overwrite
#pragma unroll
    for (int cf = 0; cf < 4; ++cf){
      int col0 = wc * 64 + cf * 16 + g2r;
#pragma unroll
      for (int rf = 0; rf < 2; ++rf){
        int row = RB + rf * 16 + c16;
        f32x4 o;
#pragma unroll
        for (int r = 0; r < 4; ++r) o[r] = fmaxf(acc[cf][rf][r] * (1.f / 16.f) + bv[cf][r], 0.f);
        *(unsigned int*)(aux + (size_t)row * 512 + (col0 ^ (c16 << 3))) =
            pack4f8(o[0], o[1], o[2], o[3]);
        tile_write(hbuf, row, col0 * 2, o);
      }
    }
    bar_lds();
    tile_store(hbuf, out_hg + (size_t)row0 * AD, AD, wid, lane);
  }

  // ---------------- Phase 3e: k / theta heads ----------------
  {
    // align XCD group before the Pk/Pt walk (site 6)
    xcd_align(gctr, 6, tid, bid, XTGT);
    ZERO_ACC(acc);
    gemm_fp8<16, 512>(aux, Pk + (size_t)(wc * 4) * 16 * 512, lane, RB, acc);
    ZERO_ACC(acc2);
    gemm_fp8<16, 512>(aux, Pt + (size_t)(wc * 4) * 16 * 512, lane, RB, acc2);
    bar_lds();   // hg bounce reads complete before overwrite
#pragma unroll
    for (int cf = 0; cf < 4; ++cf){
      int col0 = wc * 64 + cf * 16 + g2r;
      f32x4 bv = *(const f32x4*)(b_k + col0);
#pragma unroll
      for (int rf = 0; rf < 2; ++rf){
        f32x4 o;
#pragma unroll
        for (int r = 0; r < 4; ++r) o[r] = softplusf(acc[cf][rf][r] * (1.f / 16.f) + bv[r]) + 0.01f;
        tile_write(hbuf, RB + rf * 16 + c16, col0 * 2, o);
      }
    }
    bar_lds();
    tile_store(hbuf, out_k + (size_t)row0 * AD, AD, wid, lane);
    bar_lds();
#pragma unroll
    for (int cf = 0; cf < 4; ++cf){
      int col0 = wc * 64 + cf * 16 + g2r;
      f32x4 bv = *(const f32x4*)(b_t + col0);
#pragma unroll
      for (int rf = 0; rf < 2; ++rf){
        f32x4 o;
#pragma unroll
        for (int r = 0; r < 4; ++r) o[r] = softplusf(acc2[cf][rf][r] * (1.f / 16.f) + bv[r]) + 1e-4f;
        tile_write(hbuf, RB + rf * 16 + c16, col0 * 2, o);
      }
    }
    bar_lds();
    tile_store(hbuf, out_th + (size_t)row0 * AD, AD, wid, lane);
  }
}

extern "C" void kernel_launch(void* const* d_in, const int* in_sizes, int n_in,
                              void* d_out, int out_size, void* d_ws, size_t ws_size,
                              hipStream_t stream){
  (void)in_sizes; (void)n_in; (void)out_size; (void)ws_size;
  const float* x      = (const float*)d_in[0];
  const float* W_proj = (const float*)d_in[1];
  const float* b_proj = (const float*)d_in[2];
  const float* W_rec  = (const float*)d_in[3];
  const float* log_th = (const float*)d_in[4];
  const float* W_pres = (const float*)d_in[5];
  const float* b_pres = (const float*)d_in[6];
  const float* W_sign = (const float*)d_in[7];
  const float* b_sign = (const float*)d_in[8];
  const float* W_g1   = (const float*)d_in[9];
  const float* b_g1   = (const float*)d_in[10];
  const float* W_g2   = (const float*)d_in[11];
  const float* b_g2   = (const float*)d_in[12];
  const float* W_k    = (const float*)d_in[13];
  const float* b_k    = (const float*)d_in[14];
  const float* W_t    = (const float*)d_in[15];
  const float* b_t    = (const float*)d_in[16];

  unsigned char* ws = (unsigned char*)d_ws;
  pack_all<<<1536, 256, 0, stream>>>(W_proj, W_rec, W_pres, W_sign, W_g1, W_g2, W_k, W_t, ws);
  polar_main<<<256, 1024, 0, stream>>>(
      x, b_proj, log_th, b_pres, b_sign, W_g1, b_g1, b_g2, b_k, b_t,
      ws, (float*)d_out);
}

// Round 16
// 439.474 us; speedup vs baseline: 1.5918x; 1.5918x over previous
//
#include <hip/hip_runtime.h>
#include <hip/hip_fp8.h>

typedef __attribute__((ext_vector_type(8))) short short8;
typedef __attribute__((ext_vector_type(4))) float f32x4;
typedef __attribute__((ext_vector_type(2))) long longx2;   // 16B: two fp8 A-frags (ks, ks+1)

#define NB 16384
#define DDIM 1024
#define AD 512
#define CTR_OFF 3407872   // barrier counters just past the packed weights

static __device__ __forceinline__ unsigned short f2bf(float f){
  unsigned int u = __float_as_uint(f);
  u += 0x7FFFu + ((u >> 16) & 1u);
  return (unsigned short)(u >> 16);
}
static __device__ __forceinline__ float bf2f(short s){
  return __uint_as_float(((unsigned int)(unsigned short)s) << 16);
}
// SOFTWARE conversions throughout (r12/r13 lesson): HW cvt_pk asm forms cut
// VALU op count but their rigid dep-chains + register pinning block the
// scheduler in latency-critical regions. Schedulable op count beats raw op
// count here: r11=440us (SW/SW), r12=463 (HW/HW), r13=461 (SW/HW).
static __device__ __forceinline__ unsigned long long pack4(float a, float b, float c, float d){
  return (unsigned long long)f2bf(a) | ((unsigned long long)f2bf(b) << 16)
       | ((unsigned long long)f2bf(c) << 32) | ((unsigned long long)f2bf(d) << 48);
}
static __device__ __forceinline__ unsigned char f2e4(float f){
  return __hip_fp8_e4m3(f).__x;
}
static __device__ __forceinline__ unsigned int pack4f8(float a, float b, float c, float d){
  return (unsigned)f2e4(a) | ((unsigned)f2e4(b) << 8) | ((unsigned)f2e4(c) << 16) | ((unsigned)f2e4(d) << 24);
}
static __device__ __forceinline__ float softplusf(float z){
  return fmaxf(z, 0.f) + log1pf(expf(-fabsf(z)));
}
static __device__ __forceinline__ float softf(float z, float th){
  return copysignf(fmaxf(fabsf(z) - th, 0.f), z);
}

// LDS-only barrier: waits local ops, does NOT drain vmcnt.
static __device__ __forceinline__ void bar_lds(){
  __builtin_amdgcn_sched_barrier(0);
  asm volatile("s_waitcnt lgkmcnt(0)" ::: "memory");
  __builtin_amdgcn_s_barrier();
  __builtin_amdgcn_sched_barrier(0);
}

// Best-effort PER-XCD alignment barrier (PERFORMANCE ONLY). L2 sharing is a
// per-XCD phenomenon: only the 32 blocks on one XCD need to walk the weight
// addresses together (r8: FETCH 1.03GB->495MB, -37us; r11: per-XCD form
// -22us vs grid form). Bounded spin; counters reset by pack_all each launch
// (stream-ordered, graph-safe). Correctness never depends on convergence.
static __device__ __forceinline__ void xcd_align(unsigned* ctrs, int site,
                                                 int tid, unsigned bid,
                                                 unsigned target){
  unsigned* ctr = ctrs + site * 8 + (bid & 7);
  if (tid == 0){
    __hip_atomic_fetch_add(ctr, 1u, __ATOMIC_RELAXED, __HIP_MEMORY_SCOPE_AGENT);
    for (int i = 0; i < 8000; ++i){
      if (__hip_atomic_load(ctr, __ATOMIC_RELAXED, __HIP_MEMORY_SCOPE_AGENT) >= target)
        break;
      __builtin_amdgcn_s_sleep(2);
    }
  }
  bar_lds();
}

// Pack W[K][N] (f32 row-major, stride ldn) into per-lane MFMA A-fragments.
// bf16 frag: 16B/lane at (frag*64+lane)*16, frag = nt*KS+ks.
// fp8 frag: 8B/lane, PAIR-INTERLEAVED for 16B loads: byte addr =
//   (pair*64+lane)*16 + (ks&1)*8, pair = nt*(KS/2)+ks/2.
__global__ void pack_all(const float* __restrict__ W_proj, const float* __restrict__ W_rec,
                         const float* __restrict__ W_pres, const float* __restrict__ W_sign,
                         const float* __restrict__ W_g1,   const float* __restrict__ W_g2,
                         const float* __restrict__ W_k,    const float* __restrict__ W_t,
                         unsigned char* __restrict__ ws){
  if (blockIdx.x == 0 && threadIdx.x < 64)
    __hip_atomic_store((unsigned*)(ws + CTR_OFF) + threadIdx.x, 0u,
                       __ATOMIC_RELAXED, __HIP_MEMORY_SCOPE_AGENT);
  int t = blockIdx.x * 256 + threadIdx.x;
  const float* W; size_t off; int KS, NT, ldn, isbf; float scl = 16.f;
  if      (t < 32768) {              W = W_rec;                   off = 0;       KS = 16; NT = 32; ldn = 512;  isbf = 1; }
  else if (t < 98304) { t -= 32768;  W = W_proj;                  off = 524288;  KS = 32; NT = 32; ldn = 512;  isbf = 0; }
  else if (t < 163840){ t -= 98304;  W = W_pres;                  off = 1048576; KS = 16; NT = 64; ldn = 1024; isbf = 0; }
  else if (t < 196608){ t -= 163840; W = W_sign;                  off = 1572864; KS = 16; NT = 32; ldn = 512;  isbf = 0; }
  else if (t < 262144){ t -= 196608; W = W_g1;                    off = 1835008; KS = 32; NT = 32; ldn = 512;  isbf = 0; scl = 4.f; }
  else if (t < 294912){ t -= 262144; W = W_g1 + (size_t)1025*512; off = 2359296; KS = 16; NT = 32; ldn = 512;  isbf = 0; }
  else if (t < 327680){ t -= 294912; W = W_g2;                    off = 2621440; KS = 16; NT = 32; ldn = 512;  isbf = 0; }
  else if (t < 360448){ t -= 327680; W = W_k;                     off = 2883584; KS = 16; NT = 32; ldn = 512;  isbf = 0; }
  else if (t < 393216){ t -= 360448; W = W_t;                     off = 3145728; KS = 16; NT = 32; ldn = 512;  isbf = 0; }
  else return;
  int lane = t & 63;
  int frag = t >> 6;
  int ks = frag % KS;
  int nt = frag / KS;
  int col = nt * 16 + (lane & 15);
  int k0 = ks * 32 + ((lane >> 4) << 3);
  const float* src = W + (size_t)k0 * ldn + col;
  if (isbf){
    short8 v;
#pragma unroll
    for (int j = 0; j < 8; ++j) v[j] = (short)f2bf(src[(size_t)j * ldn]);
    *(short8*)(ws + off + ((size_t)frag * 64 + lane) * 16) = v;
  } else {
    unsigned long long v = 0;
#pragma unroll
    for (int j = 0; j < 8; ++j)
      v |= (unsigned long long)f2e4(src[(size_t)j * ldn] * scl) << (8 * j);
    int pair = nt * (KS >> 1) + (ks >> 1);
    *(unsigned long long*)(ws + off + ((size_t)pair * 64 + lane) * 16 + ((size_t)(ks & 1) << 3)) = v;
  }
}

// bf16 GEMM step: A (weights, packed) x B (h in LDS [64 rows][1024B], XOR<<4 swizzle).
// acc[cf=2][rf=4]. K=512 (16 ks steps). Depth-1 A-prefetch.
__device__ __forceinline__ void gemm_bf16(const unsigned char* __restrict__ hb,
    const unsigned char* __restrict__ A, int lane, f32x4 acc[2][4]){
  const int c16 = lane & 15;
  const int g16 = (lane >> 4) << 4;
  const int swz = ((c16 & 7) << 4) ^ g16;   // row&7 == c16&7 for all rf
  const unsigned char* bp[4];
#pragma unroll
  for (int rf = 0; rf < 4; ++rf) bp[rf] = hb + (size_t)(rf * 16 + c16) * 1024;
  const unsigned char* a0 = A + lane * 16;
  const unsigned char* a1 = A + 16 * 1024 + lane * 16;
  short8 af0 = *(const short8*)a0;
  short8 af1 = *(const short8*)a1;
#pragma unroll
  for (int ks = 0; ks < 16; ++ks){
    short8 c0 = af0, c1 = af1;
    if (ks < 15){
      a0 += 1024; a1 += 1024;
      af0 = *(const short8*)a0;
      af1 = *(const short8*)a1;
    }
    int kb = ks * 64;
    short8 b[4];
#pragma unroll
    for (int rf = 0; rf < 4; ++rf) b[rf] = *(const short8*)(bp[rf] + (kb ^ swz));
    __builtin_amdgcn_s_setprio(1);
#pragma unroll
    for (int rf = 0; rf < 4; ++rf){
      acc[0][rf] = __builtin_amdgcn_mfma_f32_16x16x32_bf16(c0, b[rf], acc[0][rf], 0, 0, 0);
      acc[1][rf] = __builtin_amdgcn_mfma_f32_16x16x32_bf16(c1, b[rf], acc[1][rf], 0, 0, 0);
    }
    __builtin_amdgcn_s_setprio(0);
  }
}

// fp8 GEMM step: A pair-packed (16B/lane = 2 ks-steps) -> dwordx4 loads.
// Depth-1 prefetch. B: fp8 LDS tile, row stride RS, XOR<<3 &15 swizzle.
template<int KSRUN, int RS>
__device__ __forceinline__ void gemm_fp8(const unsigned char* __restrict__ bb,
    const unsigned char* __restrict__ A, int kstot, int lane, f32x4 acc[2][4]){
  const int c16 = lane & 15;
  const int g8 = (lane >> 4) << 3;
  const int swz = (c16 << 3) ^ g8;          // row&15 == c16 for all rf
  const unsigned char* bp[4];
#pragma unroll
  for (int rf = 0; rf < 4; ++rf) bp[rf] = bb + (size_t)(rf * 16 + c16) * RS;
  const unsigned char* a0 = A + lane * 16;
  const unsigned char* a1 = A + (size_t)kstot * 512 + lane * 16;
  longx2 f0 = *(const longx2*)a0;
  longx2 f1 = *(const longx2*)a1;
#pragma unroll
  for (int p = 0; p < KSRUN / 2; ++p){
    longx2 c0 = f0, c1 = f1;
    if (p < KSRUN / 2 - 1){
      a0 += 1024; a1 += 1024;
      f0 = *(const longx2*)a0;
      f1 = *(const longx2*)a1;
    }
#pragma unroll
    for (int h = 0; h < 2; ++h){
      int kb = (p * 2 + h) * 32;
      long b[4];
#pragma unroll
      for (int rf = 0; rf < 4; ++rf) b[rf] = *(const long*)(bp[rf] + (kb ^ swz));
      __builtin_amdgcn_s_setprio(1);
#pragma unroll
      for (int rf = 0; rf < 4; ++rf){
        acc[0][rf] = __builtin_amdgcn_mfma_f32_16x16x32_fp8_fp8(c0[h], b[rf], acc[0][rf], 0, 0, 0);
        acc[1][rf] = __builtin_amdgcn_mfma_f32_16x16x32_fp8_fp8(c1[h], b[rf], acc[1][rf], 0, 0, 0);
      }
      __builtin_amdgcn_s_setprio(0);
    }
  }
}

// Dual fp8 GEMM: two A-sets sharing one pass over B. Pair-packed 16B loads.
template<int KSRUN, int RS>
__device__ __forceinline__ void gemm_fp8_dual(const unsigned char* __restrict__ bb,
    const unsigned char* __restrict__ A0, const unsigned char* __restrict__ A1,
    int kstot, int lane, f32x4 acc0[2][4], f32x4 acc1[2][4]){
  const int c16 = lane & 15;
  const int g8 = (lane >> 4) << 3;
  const int swz = (c16 << 3) ^ g8;
  const unsigned char* bp[4];
#pragma unroll
  for (int rf = 0; rf < 4; ++rf) bp[rf] = bb + (size_t)(rf * 16 + c16) * RS;
  const unsigned char* a00 = A0 + lane * 16;
  const unsigned char* a01 = A0 + (size_t)kstot * 512 + lane * 16;
  const unsigned char* a10 = A1 + lane * 16;
  const unsigned char* a11 = A1 + (size_t)kstot * 512 + lane * 16;
  longx2 f00 = *(const longx2*)a00, f01 = *(const longx2*)a01;
  longx2 f10 = *(const longx2*)a10, f11 = *(const longx2*)a11;
#pragma unroll
  for (int p = 0; p < KSRUN / 2; ++p){
    longx2 c00 = f00, c01 = f01, c10 = f10, c11 = f11;
    if (p < KSRUN / 2 - 1){
      a00 += 1024; a01 += 1024; a10 += 1024; a11 += 1024;
      f00 = *(const longx2*)a00; f01 = *(const longx2*)a01;
      f10 = *(const longx2*)a10; f11 = *(const longx2*)a11;
    }
#pragma unroll
    for (int h = 0; h < 2; ++h){
      int kb = (p * 2 + h) * 32;
      long b[4];
#pragma unroll
      for (int rf = 0; rf < 4; ++rf) b[rf] = *(const long*)(bp[rf] + (kb ^ swz));
      __builtin_amdgcn_s_setprio(1);
#pragma unroll
      for (int rf = 0; rf < 4; ++rf){
        acc0[0][rf] = __builtin_amdgcn_mfma_f32_16x16x32_fp8_fp8(c00[h], b[rf], acc0[0][rf], 0, 0, 0);
        acc0[1][rf] = __builtin_amdgcn_mfma_f32_16x16x32_fp8_fp8(c01[h], b[rf], acc0[1][rf], 0, 0, 0);
        acc1[0][rf] = __builtin_amdgcn_mfma_f32_16x16x32_fp8_fp8(c10[h], b[rf], acc1[0][rf], 0, 0, 0);
        acc1[1][rf] = __builtin_amdgcn_mfma_f32_16x16x32_fp8_fp8(c11[h], b[rf], acc1[1][rf], 0, 0, 0);
      }
      __builtin_amdgcn_s_setprio(0);
    }
  }
}

#define ZERO_ACC(A) { _Pragma("unroll") for (int c_=0;c_<2;++c_) _Pragma("unroll") for(int r_=0;r_<4;++r_){ f32x4 z_ = {0.f,0.f,0.f,0.f}; A[c_][r_]=z_; } }

// write one f32x4 (4 consecutive out-cols) as bf16x4 into the 64x512 bf16 bounce tile
static __device__ __forceinline__ void tile_write(unsigned char* tile, int row, int colb, f32x4 v){
  *(unsigned long long*)(tile + (size_t)row * 1024 + (colb ^ ((row & 7) << 4))) = pack4(v[0], v[1], v[2], v[3]);
}

// stream the 64x512 bf16 bounce tile to global f32, non-temporal.
// Full-sector form: each NT store instruction's 16-lane group covers a
// CONTIGUOUS 256B (lane stride 16B) -> no partial 64B sectors (r10: -14us,
// WRITE 434->378MB).
static __device__ __forceinline__ void tile_store(const unsigned char* __restrict__ tile,
    float* __restrict__ dst, int ldo, int wid, int lane){
  int row = wid * 4 + (lane >> 4);
  const unsigned char* rp = tile + (size_t)row * 1024;
  float* orow = dst + (size_t)row * ldo;
  int sw = (row & 7) << 4;
  int l4 = lane & 15;
#pragma unroll
  for (int j = 0; j < 8; ++j){
    int cbyte = j * 128 + l4 * 8;             // bf16 cols j*64 + l4*4 .. +3
    unsigned long long v = *(const unsigned long long*)(rp + (cbyte ^ sw));
    f32x4 o;
    o[0] = bf2f((short)v);         o[1] = bf2f((short)(v >> 16));
    o[2] = bf2f((short)(v >> 32)); o[3] = bf2f((short)(v >> 48));
    __builtin_nontemporal_store(o, (f32x4*)(orow + j * 64 + l4 * 4));
  }
}

__global__ __launch_bounds__(1024, 4) void polar_main(
    const float* __restrict__ x,
    const float* __restrict__ b_proj,
    const float* __restrict__ log_th,
    const float* __restrict__ b_pres,
    const float* __restrict__ b_sign,
    const float* __restrict__ W_g1,
    const float* __restrict__ b_g1,
    const float* __restrict__ b_g2,
    const float* __restrict__ b_k,
    const float* __restrict__ b_t,
    const unsigned char* __restrict__ ws,
    float* __restrict__ out)
{
  // LDS: hbuf 64x512 bf16 (64K) | xbuf 64x1024 fp8 (64K, x*4) | aux 64x512 fp8 (32K)
  __shared__ __align__(128) unsigned char smem[163840];
  unsigned char* hbuf = smem;
  unsigned char* xbuf = smem + 65536;
  unsigned char* aux  = smem + 131072;
  float* recip_s = (float*)aux;
  float* gain_s  = (float*)(aux + 256);

  const unsigned char* Prec  = ws;
  const unsigned char* Pproj = ws + 524288;
  const unsigned char* Ppres = ws + 1048576;
  const unsigned char* Psign = ws + 1572864;
  const unsigned char* Pg1x  = ws + 1835008;
  const unsigned char* Pg1h  = ws + 2359296;
  const unsigned char* Pg2   = ws + 2621440;
  const unsigned char* Pk    = ws + 2883584;
  const unsigned char* Pt    = ws + 3145728;
  unsigned* gctr = (unsigned*)(size_t)(ws + CTR_OFF);

  const int tid = threadIdx.x;
  const int lane = tid & 63;
  const int wid = tid >> 6;        // 0..15
  const unsigned bid = blockIdx.x;
  const int row0 = bid * 64;
  const int c16 = lane & 15;
  const int g2r = (lane >> 4) << 2;
  const unsigned XTGT = gridDim.x >> 3;   // blocks per XCD group (=32)

  float* out_k     = out;
  float* out_th    = out + (size_t)NB * AD;
  float* out_pres  = out + (size_t)2 * NB * AD;
  float* out_sign  = out + (size_t)4 * NB * AD;
  float* out_scale = out + (size_t)5 * NB * AD;
  float* out_hd    = out_scale + NB;
  float* out_hg    = out_hd + (size_t)NB * AD;

  // ---------------- Phase 1a: NT-load x, stage fp8(4x) into xbuf, row norms ----------------
  {
    int r = tid >> 4, sub = tid & 15;
    const float* xr = x + (size_t)(row0 + r) * DDIM + sub * 64;
    float ss = 0.f;
#pragma unroll
    for (int i = 0; i < 8; ++i){
      f32x4 v0 = __builtin_nontemporal_load((const f32x4*)(xr + i * 8));
      f32x4 v1 = __builtin_nontemporal_load((const f32x4*)(xr + i * 8 + 4));
      ss += v0[0]*v0[0] + v0[1]*v0[1] + v0[2]*v0[2] + v0[3]*v0[3]
          + v1[0]*v1[0] + v1[1]*v1[1] + v1[2]*v1[2] + v1[3]*v1[3];
      unsigned long long w = (unsigned long long)pack4f8(v0[0]*4.f, v0[1]*4.f, v0[2]*4.f, v0[3]*4.f)
                           | ((unsigned long long)pack4f8(v1[0]*4.f, v1[1]*4.f, v1[2]*4.f, v1[3]*4.f) << 32);
      int cbyte = sub * 64 + i * 8;
      *(unsigned long long*)(xbuf + (size_t)r * 1024 + (cbyte ^ ((r & 15) << 3))) = w;
    }
    ss += __shfl_xor(ss, 1);
    ss += __shfl_xor(ss, 2);
    ss += __shfl_xor(ss, 4);
    ss += __shfl_xor(ss, 8);
    if (sub == 0){
      float norm = sqrtf(ss);
      recip_s[r] = 1.f / (norm + 1e-6f);
      gain_s[r]  = logf(norm + 1e-6f);
      __builtin_nontemporal_store(norm, out_scale + row0 + r);
    }
  }
  bar_lds();

  float rn[4], gn[4];
#pragma unroll
  for (int rf = 0; rf < 4; ++rf){
    rn[rf] = recip_s[rf * 16 + c16];
    gn[rf] = gain_s[rf * 16 + c16];
  }

  // align XCD group before the Pproj walk (site 0)
  xcd_align(gctr, 0, tid, bid, XTGT);

  f32x4 acc[2][4];

  // ---------------- Phase 1b: drive = (x @ W_proj) * rn/64 + b ----------------
  ZERO_ACC(acc);
  gemm_fp8<32, 1024>(xbuf, Pproj + (size_t)(wid * 2) * 32 * 512, 32, lane, acc);

  f32x4 dr[2][4];
  f32x4 th4[2];
#pragma unroll
  for (int cf = 0; cf < 2; ++cf){
    int col0 = wid * 32 + cf * 16 + g2r;
    f32x4 lt = *(const f32x4*)(log_th + col0);
    f32x4 bp = *(const f32x4*)(b_proj + col0);
#pragma unroll
    for (int r = 0; r < 4; ++r) th4[cf][r] = expf(lt[r]);
#pragma unroll
    for (int rf = 0; rf < 4; ++rf)
#pragma unroll
      for (int r = 0; r < 4; ++r)
        dr[cf][rf][r] = acc[cf][rf][r] * (rn[rf] * (1.f / 64.f)) + bp[r];
  }
  // h0 -> hbuf
#pragma unroll
  for (int cf = 0; cf < 2; ++cf){
    int colb = (wid * 32 + cf * 16 + g2r) * 2;
#pragma unroll
    for (int rf = 0; rf < 4; ++rf){
      f32x4 hv;
#pragma unroll
      for (int r = 0; r < 4; ++r) hv[r] = softf(dr[cf][rf][r], th4[cf][r]);
      tile_write(hbuf, rf * 16 + c16, colb, hv);
    }
  }
  bar_lds();

  // ---------------- Phase 2: 15 LISTA iterations (bf16, h in hbuf) ----------------
  const unsigned char* Arec = Prec + (size_t)(wid * 2) * 16 * 1024;
#pragma unroll 1
  for (int it = 0; it < 15; ++it){
    if (it == 8) xcd_align(gctr, 1, tid, bid, XTGT);   // re-align mid-LISTA (site 1)
    ZERO_ACC(acc);
    gemm_bf16(hbuf, Arec, lane, acc);
    bar_lds();               // all h reads done before overwrite
#pragma unroll
    for (int cf = 0; cf < 2; ++cf){
      int col0 = wid * 32 + cf * 16 + g2r;
#pragma unroll
      for (int rf = 0; rf < 4; ++rf){
        int row = rf * 16 + c16;
        f32x4 hv;
#pragma unroll
        for (int r = 0; r < 4; ++r)
          hv[r] = softf(dr[cf][rf][r] + acc[cf][rf][r], th4[cf][r]);
        tile_write(hbuf, row, col0 * 2, hv);
        if (it == 14)          // also stage h as fp8 for phase 3
          *(unsigned int*)(aux + (size_t)row * 512 + (col0 ^ (c16 << 3))) =
              pack4f8(hv[0], hv[1], hv[2], hv[3]);
      }
    }
    bar_lds();
  }

  // ---------------- Phase 3: heads ----------------
  f32x4 acc2[2][4];

  // align XCD group before the Ppres walk (site 2)
  xcd_align(gctr, 2, tid, bid, XTGT);

  // h_delta out (bounce = hbuf itself, already bf16); NT stores drain under
  // the pres GEMM that follows (no vmcnt drain at barriers).
  tile_store(hbuf, out_hd + (size_t)row0 * AD, AD, wid, lane);

  // 3a: presence (1024 cols) — both halves in ONE pass over B (shared aux reads)
  ZERO_ACC(acc);
  ZERO_ACC(acc2);
  gemm_fp8_dual<16, 512>(aux,
      Ppres + (size_t)(wid * 2) * 16 * 512,
      Ppres + (size_t)(32 + wid * 2) * 16 * 512, 16, lane, acc, acc2);
  bar_lds();                   // h_delta reads of hbuf complete

  // write + store pres half 0
#pragma unroll
  for (int cf = 0; cf < 2; ++cf){
    int col0 = (wid * 2 + cf) * 16 + g2r;
    f32x4 bv = *(const f32x4*)(b_pres + col0);
    int colb = (wid * 32 + cf * 16 + g2r) * 2;
#pragma unroll
    for (int rf = 0; rf < 4; ++rf){
      f32x4 o;
#pragma unroll
      for (int r = 0; r < 4; ++r) o[r] = acc[cf][rf][r] * (1.f / 16.f) + bv[r];
      tile_write(hbuf, rf * 16 + c16, colb, o);
    }
  }
  bar_lds();
  tile_store(hbuf, out_pres + (size_t)row0 * 1024, 1024, wid, lane);

  // align XCD group before the Psign walk (site 4 — cheap as per-XCD)
  xcd_align(gctr, 4, tid, bid, XTGT);

  // 3b: sign GEMM issued here — its A-stream overlaps the pres-half1 bounce cycle
  ZERO_ACC(acc);
  gemm_fp8<16, 512>(aux, Psign + (size_t)(wid * 2) * 16 * 512, 16, lane, acc);
  bar_lds();                   // pres-half0 bounce reads complete

  // write + store pres half 1
#pragma unroll
  for (int cf = 0; cf < 2; ++cf){
    int col0 = (32 + wid * 2 + cf) * 16 + g2r;
    f32x4 bv = *(const f32x4*)(b_pres + col0);
    int colb = (wid * 32 + cf * 16 + g2r) * 2;
#pragma unroll
    for (int rf = 0; rf < 4; ++rf){
      f32x4 o;
#pragma unroll
      for (int r = 0; r < 4; ++r) o[r] = acc2[cf][rf][r] * (1.f / 16.f) + bv[r];
      tile_write(hbuf, rf * 16 + c16, colb, o);
    }
  }
  bar_lds();
  tile_store(hbuf, out_pres + (size_t)row0 * 1024 + 512, 1024, wid, lane);
  bar_lds();

  // write + store sign
#pragma unroll
  for (int cf = 0; cf < 2; ++cf){
    int col0 = wid * 32 + cf * 16 + g2r;
    f32x4 bv = *(const f32x4*)(b_sign + col0);
#pragma unroll
    for (int rf = 0; rf < 4; ++rf){
      f32x4 o;
#pragma unroll
      for (int r = 0; r < 4; ++r) o[r] = acc[cf][rf][r] * (1.f / 16.f) + bv[r];
      tile_write(hbuf, rf * 16 + c16, col0 * 2, o);
    }
  }
  bar_lds();
  tile_store(hbuf, out_sign + (size_t)row0 * AD, AD, wid, lane);

  // align XCD group before the gamma-chain weight walk (site 3)
  xcd_align(gctr, 3, tid, bid, XTGT);

  // ---------------- Phase 3c: hg1 = relu(x@Wg1x + h@Wg1h/16 + gain*wg + b) ----------------
  // Pg1x packed at x4 -> x(4)*w(4)=16, matches h(1)*w(16)=16: single /16 epilogue.
  {
    ZERO_ACC(acc);
    gemm_fp8<32, 1024>(xbuf, Pg1x + (size_t)(wid * 2) * 32 * 512, 32, lane, acc);
    gemm_fp8<16, 512>(aux, Pg1h + (size_t)(wid * 2) * 16 * 512, 16, lane, acc);

    f32x4 bv[2], wg[2];
#pragma unroll
    for (int cf = 0; cf < 2; ++cf){
      int col0 = wid * 32 + cf * 16 + g2r;
      bv[cf] = *(const f32x4*)(b_g1 + col0);
      wg[cf] = *(const f32x4*)(W_g1 + (size_t)1024 * AD + col0);
    }
    bar_lds();   // all aux (h-fp8) reads done before overwrite
#pragma unroll
    for (int cf = 0; cf < 2; ++cf){
      int col0 = wid * 32 + cf * 16 + g2r;
#pragma unroll
      for (int rf = 0; rf < 4; ++rf){
        int row = rf * 16 + c16;
        float z0 = fmaxf(acc[cf][rf][0] * (1.f/16.f) + gn[rf] * wg[cf][0] + bv[cf][0], 0.f);
        float z1 = fmaxf(acc[cf][rf][1] * (1.f/16.f) + gn[rf] * wg[cf][1] + bv[cf][1], 0.f);
        float z2 = fmaxf(acc[cf][rf][2] * (1.f/16.f) + gn[rf] * wg[cf][2] + bv[cf][2], 0.f);
        float z3 = fmaxf(acc[cf][rf][3] * (1.f/16.f) + gn[rf] * wg[cf][3] + bv[cf][3], 0.f);
        *(unsigned int*)(aux + (size_t)row * 512 + (col0 ^ (c16 << 3))) =
            pack4f8(z0, z1, z2, z3);
      }
    }
    bar_lds();
  }

  // ---------------- Phase 3d: hg = relu(hg1 @ W_g2 /16 + b_g2) ----------------
  {
    // align XCD group before the Pg2 walk (site 5)
    xcd_align(gctr, 5, tid, bid, XTGT);
    ZERO_ACC(acc);
    gemm_fp8<16, 512>(aux, Pg2 + (size_t)(wid * 2) * 16 * 512, 16, lane, acc);
    f32x4 bv[2];
#pragma unroll
    for (int cf = 0; cf < 2; ++cf)
      bv[cf] = *(const f32x4*)(b_g2 + wid * 32 + cf * 16 + g2r);
    bar_lds();   // all hg1 reads done before overwrite
#pragma unroll
    for (int cf = 0; cf < 2; ++cf){
      int col0 = wid * 32 + cf * 16 + g2r;
#pragma unroll
      for (int rf = 0; rf < 4; ++rf){
        int row = rf * 16 + c16;
        f32x4 o;
#pragma unroll
        for (int r = 0; r < 4; ++r) o[r] = fmaxf(acc[cf][rf][r] * (1.f / 16.f) + bv[cf][r], 0.f);
        *(unsigned int*)(aux + (size_t)row * 512 + (col0 ^ (c16 << 3))) =
            pack4f8(o[0], o[1], o[2], o[3]);
        tile_write(hbuf, row, col0 * 2, o);
      }
    }
    bar_lds();
    tile_store(hbuf, out_hg + (size_t)row0 * AD, AD, wid, lane);
  }

  // ---------------- Phase 3e: k / theta heads — ONE pass over B ----------------
  {
    // align XCD group before the Pk/Pt walk (site 6)
    xcd_align(gctr, 6, tid, bid, XTGT);
    ZERO_ACC(acc);
    ZERO_ACC(acc2);
    gemm_fp8_dual<16, 512>(aux,
        Pk + (size_t)(wid * 2) * 16 * 512,
        Pt + (size_t)(wid * 2) * 16 * 512, 16, lane, acc, acc2);
    bar_lds();   // hg bounce reads complete before overwrite
#pragma unroll
    for (int cf = 0; cf < 2; ++cf){
      int col0 = wid * 32 + cf * 16 + g2r;
      f32x4 bv = *(const f32x4*)(b_k + col0);
#pragma unroll
      for (int rf = 0; rf < 4; ++rf){
        f32x4 o;
#pragma unroll
        for (int r = 0; r < 4; ++r) o[r] = softplusf(acc[cf][rf][r] * (1.f / 16.f) + bv[r]) + 0.01f;
        tile_write(hbuf, rf * 16 + c16, col0 * 2, o);
      }
    }
    bar_lds();
    tile_store(hbuf, out_k + (size_t)row0 * AD, AD, wid, lane);
    bar_lds();
#pragma unroll
    for (int cf = 0; cf < 2; ++cf){
      int col0 = wid * 32 + cf * 16 + g2r;
      f32x4 bv = *(const f32x4*)(b_t + col0);
#pragma unroll
      for (int rf = 0; rf < 4; ++rf){
        f32x4 o;
#pragma unroll
        for (int r = 0; r < 4; ++r) o[r] = softplusf(acc2[cf][rf][r] * (1.f / 16.f) + bv[r]) + 1e-4f;
        tile_write(hbuf, rf * 16 + c16, col0 * 2, o);
      }
    }
    bar_lds();
    tile_store(hbuf, out_th + (size_t)row0 * AD, AD, wid, lane);
  }
}

extern "C" void kernel_launch(void* const* d_in, const int* in_sizes, int n_in,
                              void* d_out, int out_size, void* d_ws, size_t ws_size,
                              hipStream_t stream){
  (void)in_sizes; (void)n_in; (void)out_size; (void)ws_size;
  const float* x      = (const float*)d_in[0];
  const float* W_proj = (const float*)d_in[1];
  const float* b_proj = (const float*)d_in[2];
  const float* W_rec  = (const float*)d_in[3];
  const float* log_th = (const float*)d_in[4];
  const float* W_pres = (const float*)d_in[5];
  const float* b_pres = (const float*)d_in[6];
  const float* W_sign = (const float*)d_in[7];
  const float* b_sign = (const float*)d_in[8];
  const float* W_g1   = (const float*)d_in[9];
  const float* b_g1   = (const float*)d_in[10];
  const float* W_g2   = (const float*)d_in[11];
  const float* b_g2   = (const float*)d_in[12];
  const float* W_k    = (const float*)d_in[13];
  const float* b_k    = (const float*)d_in[14];
  const float* W_t    = (const float*)d_in[15];
  const float* b_t    = (const float*)d_in[16];

  unsigned char* ws = (unsigned char*)d_ws;
  pack_all<<<1536, 256, 0, stream>>>(W_proj, W_rec, W_pres, W_sign, W_g1, W_g2, W_k, W_t, ws);
  polar_main<<<256, 1024, 0, stream>>>(
      x, b_proj, log_th, b_pres, b_sign, W_g1, b_g1, b_g2, b_k, b_t,
      ws, (float*)d_out);
}